// Round 16
// baseline (228.253 us; speedup 1.0000x reference)
//
#include <hip/hip_runtime.h>

// GCN: out = Ahat( relu( Ahat(x@W1) + b1 ) @ W2 ) + b2,  Ahat = D^-1/2 (A+I) D^-1/2
// N=10000, E=640000, IN=128, HID=128, OUT=64.
// r3:  CSR gather formulation. r5: 8-deep MLP gather (50->~43us).
// r9:  fixed-slot binning (236->194us). r11: fill batching NULL (fill pinned
//      ~43.5us by E line-touches with zero temporal locality -> ~floor).
// r12: dinv/ovf folded (190.8). r13: fp16 FAILED post-timing gate (reverted).
// r14: GEMM unroll NULL. r15: gather depth 16 NULL (186.6) => all issue-side
//      levers exhausted; budget model underdetermined (gather vs gap split
//      unknown across ~50us).
// r16: MEASUREMENT ROUND. gather1 and gather2 are idempotent overwrites ->
//      launch each twice. dur_us delta vs 186.6 = g1 + g2 + 2 gaps, exactly.
//      Pre-committed: >=75 -> gathers dominate, attack lines (split-plane);
//      <=30 -> gaps/gemms are the hole, attack with cooperative fusion.

static constexpr int IN_F  = 128;
static constexpr int HID_F = 128;
static constexpr int OUT_F = 64;
static constexpr int SLOT  = 128;   // slots per node
static constexpr int OVCAP = 4096;  // overflow list capacity

__device__ __forceinline__ void push_edge(int s, int d, int* cnt, int* slots,
                                          int* ovf_cnt, int2* ovf) {
  int pos = atomicAdd(&cnt[d], 1);
  if (pos < SLOT) {
    slots[(long)d * SLOT + pos] = s;
  } else {
    int op = atomicAdd(ovf_cnt, 1);
    if (op < OVCAP) ovf[op] = make_int2(s, d);
  }
}

// UNCHANGED (control): pinned at ~43.5us by memory-system throughput.
__global__ void fill_slot_k(const int* __restrict__ src, const int* __restrict__ dst,
                            int* __restrict__ cnt, int* __restrict__ slots,
                            int* __restrict__ ovf_cnt, int2* __restrict__ ovf, int E) {
  const int t  = blockIdx.x * blockDim.x + threadIdx.x;
  const int e0 = t * 4;
  if (e0 >= E) return;
  if (((E & 3) == 0) && (e0 + 4 <= E)) {
    const int4 s4 = *reinterpret_cast<const int4*>(src + e0);
    const int4 d4 = *reinterpret_cast<const int4*>(dst + e0);
    const int p0 = atomicAdd(&cnt[d4.x], 1);
    const int p1 = atomicAdd(&cnt[d4.y], 1);
    const int p2 = atomicAdd(&cnt[d4.z], 1);
    const int p3 = atomicAdd(&cnt[d4.w], 1);
    if (p0 < SLOT) slots[(long)d4.x * SLOT + p0] = s4.x;
    else { int op = atomicAdd(ovf_cnt, 1); if (op < OVCAP) ovf[op] = make_int2(s4.x, d4.x); }
    if (p1 < SLOT) slots[(long)d4.y * SLOT + p1] = s4.y;
    else { int op = atomicAdd(ovf_cnt, 1); if (op < OVCAP) ovf[op] = make_int2(s4.y, d4.y); }
    if (p2 < SLOT) slots[(long)d4.z * SLOT + p2] = s4.z;
    else { int op = atomicAdd(ovf_cnt, 1); if (op < OVCAP) ovf[op] = make_int2(s4.z, d4.z); }
    if (p3 < SLOT) slots[(long)d4.w * SLOT + p3] = s4.w;
    else { int op = atomicAdd(ovf_cnt, 1); if (op < OVCAP) ovf[op] = make_int2(s4.w, d4.w); }
  } else {
    const int e1 = min(e0 + 4, E);
    for (int e = e0; e < e1; ++e) push_edge(src[e], dst[e], cnt, slots, ovf_cnt, ovf);
  }
}

// hs[n][f] = (sum_k in'[n][k] * W[k][f]) / sqrt(cnt[n]+1)
template<int K, int F, int NB, bool RELU_BIAS>
__global__ __launch_bounds__(F) void gemm_scale_k(
    const float* __restrict__ in, const float* __restrict__ W,
    const float* __restrict__ bin, const int* __restrict__ cnt,
    float* __restrict__ hs, int N) {
  __shared__ float xs[NB][K];
  const int f  = threadIdx.x;
  const int n0 = blockIdx.x * NB;

  for (int i = 0; i < NB; ++i) {
    int n = n0 + i;
    for (int k = f; k < K; k += F) {
      float v = (n < N) ? in[(long)n * K + k] : 0.0f;
      if (RELU_BIAS) v = fmaxf(v + bin[k], 0.0f);
      xs[i][k] = v;
    }
  }
  __syncthreads();

  float acc[NB];
#pragma unroll
  for (int i = 0; i < NB; ++i) acc[i] = 0.0f;

#pragma unroll 8
  for (int k = 0; k < K; ++k) {
    float w = W[k * F + f];
#pragma unroll
    for (int i = 0; i < NB; ++i) acc[i] = fmaf(xs[i][k], w, acc[i]);
  }

  for (int i = 0; i < NB; ++i) {
    int n = n0 + i;
    if (n < N) {
      const float di = 1.0f / sqrtf((float)(cnt[n] + 1));
      hs[(long)n * F + f] = acc[i] * di;
    }
  }
}

// One wave per node: out[n] = dinv[n]*(hs[n] + sum_slots hs[src] + ovf) [+ bias]
// Pure overwrite of `out` -> idempotent (measurement duplicates are safe).
template<int F, bool ADD_BIAS>
__global__ __launch_bounds__(256) void gather_slot_k(
    const int* __restrict__ cnt, const int* __restrict__ slots,
    const int* __restrict__ ovf_cnt, const int2* __restrict__ ovf,
    const float* __restrict__ hs, const float* __restrict__ bias,
    float* __restrict__ out, int N) {
  const int wid  = (int)((blockIdx.x * blockDim.x + threadIdx.x) >> 6);
  const int lane = threadIdx.x & 63;
  if (wid >= N) return;
  const int craw = __builtin_amdgcn_readfirstlane(cnt[wid]);
  const int deg  = min(craw, SLOT);
  const long base = (long)wid * SLOT;

  float ax, ay = 0.0f;
  if (F == 128) {
    const float2 v = *reinterpret_cast<const float2*>(hs + (long)wid * 128 + lane * 2);
    ax = v.x; ay = v.y;
  } else {
    ax = hs[(long)wid * 64 + lane];
  }

  int j = 0;
  for (; j + 16 <= deg; j += 16) {
    int sv[16];
#pragma unroll
    for (int u = 0; u < 16; ++u) sv[u] = slots[base + j + u];
    if (F == 128) {
      float2 hv[16];
#pragma unroll
      for (int u = 0; u < 16; ++u)
        hv[u] = *reinterpret_cast<const float2*>(hs + (long)sv[u] * 128 + lane * 2);
      float sx0 = 0.f, sy0 = 0.f, sx1 = 0.f, sy1 = 0.f;
#pragma unroll
      for (int u = 0; u < 16; u += 2) {
        sx0 += hv[u].x;     sy0 += hv[u].y;
        sx1 += hv[u + 1].x; sy1 += hv[u + 1].y;
      }
      ax += sx0 + sx1; ay += sy0 + sy1;
    } else {
      float hv[16];
#pragma unroll
      for (int u = 0; u < 16; ++u) hv[u] = hs[(long)sv[u] * 64 + lane];
      float s0 = 0.f, s1 = 0.f;
#pragma unroll
      for (int u = 0; u < 16; u += 2) { s0 += hv[u]; s1 += hv[u + 1]; }
      ax += s0 + s1;
    }
  }
  for (; j + 4 <= deg; j += 4) {
    int sv[4];
#pragma unroll
    for (int u = 0; u < 4; ++u) sv[u] = slots[base + j + u];
    if (F == 128) {
      float2 hv[4];
#pragma unroll
      for (int u = 0; u < 4; ++u)
        hv[u] = *reinterpret_cast<const float2*>(hs + (long)sv[u] * 128 + lane * 2);
#pragma unroll
      for (int u = 0; u < 4; ++u) { ax += hv[u].x; ay += hv[u].y; }
    } else {
      float hv[4];
#pragma unroll
      for (int u = 0; u < 4; ++u) hv[u] = hs[(long)sv[u] * 64 + lane];
#pragma unroll
      for (int u = 0; u < 4; ++u) ax += hv[u];
    }
  }
  for (; j < deg; ++j) {
    const int s = slots[base + j];
    if (F == 128) {
      const float2 v = *reinterpret_cast<const float2*>(hs + (long)s * 128 + lane * 2);
      ax += v.x; ay += v.y;
    } else {
      ax += hs[(long)s * 64 + lane];
    }
  }

  {
    int m = __builtin_amdgcn_readfirstlane(*ovf_cnt);
    m = min(m, OVCAP);
    for (int i = 0; i < m; ++i) {
      const int2 p = ovf[i];
      if (p.y == wid) {
        if (F == 128) {
          const float2 v = *reinterpret_cast<const float2*>(hs + (long)p.x * 128 + lane * 2);
          ax += v.x; ay += v.y;
        } else {
          ax += hs[(long)p.x * 64 + lane];
        }
      }
    }
  }

  const float di = 1.0f / sqrtf((float)(craw + 1));
  if (F == 128) {
    float2 r; r.x = ax * di; r.y = ay * di;
    *reinterpret_cast<float2*>(out + (long)wid * 128 + lane * 2) = r;
  } else {
    float v = ax * di;
    if (ADD_BIAS) v += bias[lane];
    out[(long)wid * 64 + lane] = v;
  }
}

extern "C" void kernel_launch(void* const* d_in, const int* in_sizes, int n_in,
                              void* d_out, int out_size, void* d_ws, size_t ws_size,
                              hipStream_t stream) {
  const float* x  = (const float*)d_in[0];
  const float* W1 = (const float*)d_in[1];
  const float* b1 = (const float*)d_in[2];
  const float* W2 = (const float*)d_in[3];
  const float* b2 = (const float*)d_in[4];
  const int*   ei = (const int*)d_in[5];

  const int N = in_sizes[0] / IN_F;
  const int E = in_sizes[5] / 2;
  const int* src = ei;        // edge_index[0]
  const int* dst = ei + E;    // edge_index[1]
  float* out = (float*)d_out; // [N, 64]

  // workspace layout
  const int Npad = (N + 256) & ~255;
  int*   cnt     = (int*)d_ws;                         // N counters + ovf_cnt at cnt[N]
  int*   ovf_cnt = cnt + N;                            // 1 (contiguous with cnt)
  int2*  ovf     = (int2*)(cnt + Npad);                // OVCAP pairs
  int*   slots   = (int*)(ovf + OVCAP);                // N*SLOT ints
  float* hs1     = (float*)(slots + (size_t)N * SLOT); // N*128 floats
  float* agg1    = hs1 + (size_t)N * HID_F;            // N*128 floats
  float* hs2     = hs1;                                // reuse: dead after gather-1

  const int B = 256;
  constexpr int NB = 8;

  // ---- binning (shared by both layers) ----
  hipMemsetAsync(cnt, 0, (size_t)(N + 1) * sizeof(int), stream);  // cnt + ovf_cnt
  fill_slot_k<<<((E + 3) / 4 + B - 1) / B, B, 0, stream>>>(src, dst, cnt, slots,
                                                           ovf_cnt, ovf, E);

  // ---- layer 1 ----
  gemm_scale_k<IN_F, HID_F, NB, false>
      <<<(N + NB - 1) / NB, HID_F, 0, stream>>>(x, W1, nullptr, cnt, hs1, N);
  gather_slot_k<HID_F, false>
      <<<((size_t)N * 64 + B - 1) / B, B, 0, stream>>>(cnt, slots, ovf_cnt, ovf,
                                                       hs1, nullptr, agg1, N);
  // r16 MEASUREMENT: duplicate (idempotent overwrite of agg1). Delta in dur_us
  // = gather1 time + 1 gap. Same work every call; remove next round.
  gather_slot_k<HID_F, false>
      <<<((size_t)N * 64 + B - 1) / B, B, 0, stream>>>(cnt, slots, ovf_cnt, ovf,
                                                       hs1, nullptr, agg1, N);

  // ---- layer 2 (b1+relu folded into GEMM load; b2 folded into gather store) ----
  gemm_scale_k<HID_F, OUT_F, NB, true>
      <<<(N + NB - 1) / NB, OUT_F, 0, stream>>>(agg1, W2, b1, cnt, hs2, N);
  gather_slot_k<OUT_F, true>
      <<<((size_t)N * 64 + B - 1) / B, B, 0, stream>>>(cnt, slots, ovf_cnt, ovf,
                                                       hs2, b2, out, N);
  // r16 MEASUREMENT: duplicate (idempotent overwrite of out).
  gather_slot_k<OUT_F, true>
      <<<((size_t)N * 64 + B - 1) / B, B, 0, stream>>>(cnt, slots, ovf_cnt, ovf,
                                                       hs2, b2, out, N);
}

// Round 17
// 181.739 us; speedup vs baseline: 1.2559x; 1.2559x over previous
//
#include <hip/hip_runtime.h>

// GCN: out = Ahat( relu( Ahat(x@W1) + b1 ) @ W2 ) + b2,  Ahat = D^-1/2 (A+I) D^-1/2
// N=10000, E=640000, IN=128, HID=128, OUT=64.
// r3:  CSR gather. r5: 8-deep MLP gather. r9: fixed-slot binning (236->194).
// r11: fill batching NULL (pinned by partial-line writebacks, ~43.5us).
// r12: dinv/ovf folded (190.8). r13: fp16 failed post-timing gate (reverted).
// r14: GEMM W-load unroll NULL. r15: gather depth16 NULL (186.6).
// r16: MEASURED g1+g2+2gaps = 41.6us; gap ~1us (from r9->r12 launch-count
//      datum) => GEMMs are the residual ~96us (!). LDS b32 broadcast storm:
//      2.56M+1.28M ds_read_b32 -- that's why r14 was null (wrong chain).
// r17: (a) GEMM k-loop steps by 4 with float4 LDS broadcast reads (4x fewer
//      LDS instr); (b) slots -> u16 (src<65536): halves fill's partial-line
//      writebacks (35MB->~18MB) and turns gather index reads into 2 uniform
//      uint4 loads per 16 edges; (c) r16 measurement dups removed.

static constexpr int IN_F  = 128;
static constexpr int HID_F = 128;
static constexpr int OUT_F = 64;
static constexpr int SLOT  = 128;   // slots per node
static constexpr int OVCAP = 4096;  // overflow list capacity

__device__ __forceinline__ void push_edge(int s, int d, int* cnt,
                                          unsigned short* slots,
                                          int* ovf_cnt, int2* ovf) {
  int pos = atomicAdd(&cnt[d], 1);
  if (pos < SLOT) {
    slots[(long)d * SLOT + pos] = (unsigned short)s;
  } else {
    int op = atomicAdd(ovf_cnt, 1);
    if (op < OVCAP) ovf[op] = make_int2(s, d);
  }
}

__global__ void fill_slot_k(const int* __restrict__ src, const int* __restrict__ dst,
                            int* __restrict__ cnt, unsigned short* __restrict__ slots,
                            int* __restrict__ ovf_cnt, int2* __restrict__ ovf, int E) {
  const int t  = blockIdx.x * blockDim.x + threadIdx.x;
  const int e0 = t * 4;
  if (e0 >= E) return;
  if (((E & 3) == 0) && (e0 + 4 <= E)) {
    const int4 s4 = *reinterpret_cast<const int4*>(src + e0);
    const int4 d4 = *reinterpret_cast<const int4*>(dst + e0);
    const int p0 = atomicAdd(&cnt[d4.x], 1);
    const int p1 = atomicAdd(&cnt[d4.y], 1);
    const int p2 = atomicAdd(&cnt[d4.z], 1);
    const int p3 = atomicAdd(&cnt[d4.w], 1);
    if (p0 < SLOT) slots[(long)d4.x * SLOT + p0] = (unsigned short)s4.x;
    else { int op = atomicAdd(ovf_cnt, 1); if (op < OVCAP) ovf[op] = make_int2(s4.x, d4.x); }
    if (p1 < SLOT) slots[(long)d4.y * SLOT + p1] = (unsigned short)s4.y;
    else { int op = atomicAdd(ovf_cnt, 1); if (op < OVCAP) ovf[op] = make_int2(s4.y, d4.y); }
    if (p2 < SLOT) slots[(long)d4.z * SLOT + p2] = (unsigned short)s4.z;
    else { int op = atomicAdd(ovf_cnt, 1); if (op < OVCAP) ovf[op] = make_int2(s4.z, d4.z); }
    if (p3 < SLOT) slots[(long)d4.w * SLOT + p3] = (unsigned short)s4.w;
    else { int op = atomicAdd(ovf_cnt, 1); if (op < OVCAP) ovf[op] = make_int2(s4.w, d4.w); }
  } else {
    const int e1 = min(e0 + 4, E);
    for (int e = e0; e < e1; ++e) push_edge(src[e], dst[e], cnt, slots, ovf_cnt, ovf);
  }
}

// hs[n][f] = (sum_k in'[n][k] * W[k][f]) / sqrt(cnt[n]+1)
// r17: k-loop steps by 4; xs read as float4 broadcast (LDS instr / 4).
template<int K, int F, int NB, bool RELU_BIAS>
__global__ __launch_bounds__(F) void gemm_scale_k(
    const float* __restrict__ in, const float* __restrict__ W,
    const float* __restrict__ bin, const int* __restrict__ cnt,
    float* __restrict__ hs, int N) {
  __shared__ float xs[NB][K];
  const int f  = threadIdx.x;
  const int n0 = blockIdx.x * NB;

  for (int i = 0; i < NB; ++i) {
    int n = n0 + i;
    for (int k = f; k < K; k += F) {
      float v = (n < N) ? in[(long)n * K + k] : 0.0f;
      if (RELU_BIAS) v = fmaxf(v + bin[k], 0.0f);
      xs[i][k] = v;
    }
  }
  __syncthreads();

  float acc[NB];
#pragma unroll
  for (int i = 0; i < NB; ++i) acc[i] = 0.0f;

#pragma unroll 2
  for (int k = 0; k < K; k += 4) {
    const float w0 = W[(k + 0) * F + f];
    const float w1 = W[(k + 1) * F + f];
    const float w2 = W[(k + 2) * F + f];
    const float w3 = W[(k + 3) * F + f];
#pragma unroll
    for (int i = 0; i < NB; ++i) {
      const float4 xv = *reinterpret_cast<const float4*>(&xs[i][k]);
      acc[i] = fmaf(xv.x, w0, acc[i]);
      acc[i] = fmaf(xv.y, w1, acc[i]);
      acc[i] = fmaf(xv.z, w2, acc[i]);
      acc[i] = fmaf(xv.w, w3, acc[i]);
    }
  }

  for (int i = 0; i < NB; ++i) {
    int n = n0 + i;
    if (n < N) {
      const float di = 1.0f / sqrtf((float)(cnt[n] + 1));
      hs[(long)n * F + f] = acc[i] * di;
    }
  }
}

// One wave per node: out[n] = dinv[n]*(hs[n] + sum_slots hs[src] + ovf) [+ bias]
// r17: u16 slot indices, unpacked from wave-uniform uint4/uint2 loads.
template<int F, bool ADD_BIAS>
__global__ __launch_bounds__(256) void gather_slot_k(
    const int* __restrict__ cnt, const unsigned short* __restrict__ slots,
    const int* __restrict__ ovf_cnt, const int2* __restrict__ ovf,
    const float* __restrict__ hs, const float* __restrict__ bias,
    float* __restrict__ out, int N) {
  const int wid  = (int)((blockIdx.x * blockDim.x + threadIdx.x) >> 6);
  const int lane = threadIdx.x & 63;
  if (wid >= N) return;
  const int craw = __builtin_amdgcn_readfirstlane(cnt[wid]);
  const int deg  = min(craw, SLOT);
  const long base = (long)wid * SLOT;

  float ax, ay = 0.0f;
  if (F == 128) {
    const float2 v = *reinterpret_cast<const float2*>(hs + (long)wid * 128 + lane * 2);
    ax = v.x; ay = v.y;
  } else {
    ax = hs[(long)wid * 64 + lane];
  }

  int j = 0;
  for (; j + 16 <= deg; j += 16) {
    const uint4 r0 = *reinterpret_cast<const uint4*>(slots + base + j);
    const uint4 r1 = *reinterpret_cast<const uint4*>(slots + base + j + 8);
    const int sv[16] = {
      (int)(r0.x & 0xffff), (int)(r0.x >> 16), (int)(r0.y & 0xffff), (int)(r0.y >> 16),
      (int)(r0.z & 0xffff), (int)(r0.z >> 16), (int)(r0.w & 0xffff), (int)(r0.w >> 16),
      (int)(r1.x & 0xffff), (int)(r1.x >> 16), (int)(r1.y & 0xffff), (int)(r1.y >> 16),
      (int)(r1.z & 0xffff), (int)(r1.z >> 16), (int)(r1.w & 0xffff), (int)(r1.w >> 16)};
    if (F == 128) {
      float2 hv[16];
#pragma unroll
      for (int u = 0; u < 16; ++u)
        hv[u] = *reinterpret_cast<const float2*>(hs + (long)sv[u] * 128 + lane * 2);
      float sx0 = 0.f, sy0 = 0.f, sx1 = 0.f, sy1 = 0.f;
#pragma unroll
      for (int u = 0; u < 16; u += 2) {
        sx0 += hv[u].x;     sy0 += hv[u].y;
        sx1 += hv[u + 1].x; sy1 += hv[u + 1].y;
      }
      ax += sx0 + sx1; ay += sy0 + sy1;
    } else {
      float hv[16];
#pragma unroll
      for (int u = 0; u < 16; ++u) hv[u] = hs[(long)sv[u] * 64 + lane];
      float s0 = 0.f, s1 = 0.f;
#pragma unroll
      for (int u = 0; u < 16; u += 2) { s0 += hv[u]; s1 += hv[u + 1]; }
      ax += s0 + s1;
    }
  }
  for (; j + 4 <= deg; j += 4) {
    const uint2 r = *reinterpret_cast<const uint2*>(slots + base + j);
    const int sv[4] = {(int)(r.x & 0xffff), (int)(r.x >> 16),
                       (int)(r.y & 0xffff), (int)(r.y >> 16)};
    if (F == 128) {
      float2 hv[4];
#pragma unroll
      for (int u = 0; u < 4; ++u)
        hv[u] = *reinterpret_cast<const float2*>(hs + (long)sv[u] * 128 + lane * 2);
#pragma unroll
      for (int u = 0; u < 4; ++u) { ax += hv[u].x; ay += hv[u].y; }
    } else {
      float hv[4];
#pragma unroll
      for (int u = 0; u < 4; ++u) hv[u] = hs[(long)sv[u] * 64 + lane];
#pragma unroll
      for (int u = 0; u < 4; ++u) ax += hv[u];
    }
  }
  for (; j < deg; ++j) {
    const int s = slots[base + j];
    if (F == 128) {
      const float2 v = *reinterpret_cast<const float2*>(hs + (long)s * 128 + lane * 2);
      ax += v.x; ay += v.y;
    } else {
      ax += hs[(long)s * 64 + lane];
    }
  }

  // overflow fold (expected empty)
  {
    int m = __builtin_amdgcn_readfirstlane(*ovf_cnt);
    m = min(m, OVCAP);
    for (int i = 0; i < m; ++i) {
      const int2 p = ovf[i];
      if (p.y == wid) {
        if (F == 128) {
          const float2 v = *reinterpret_cast<const float2*>(hs + (long)p.x * 128 + lane * 2);
          ax += v.x; ay += v.y;
        } else {
          ax += hs[(long)p.x * 64 + lane];
        }
      }
    }
  }

  const float di = 1.0f / sqrtf((float)(craw + 1));
  if (F == 128) {
    float2 r; r.x = ax * di; r.y = ay * di;
    *reinterpret_cast<float2*>(out + (long)wid * 128 + lane * 2) = r;
  } else {
    float v = ax * di;
    if (ADD_BIAS) v += bias[lane];
    out[(long)wid * 64 + lane] = v;
  }
}

extern "C" void kernel_launch(void* const* d_in, const int* in_sizes, int n_in,
                              void* d_out, int out_size, void* d_ws, size_t ws_size,
                              hipStream_t stream) {
  const float* x  = (const float*)d_in[0];
  const float* W1 = (const float*)d_in[1];
  const float* b1 = (const float*)d_in[2];
  const float* W2 = (const float*)d_in[3];
  const float* b2 = (const float*)d_in[4];
  const int*   ei = (const int*)d_in[5];

  const int N = in_sizes[0] / IN_F;
  const int E = in_sizes[5] / 2;
  const int* src = ei;        // edge_index[0]
  const int* dst = ei + E;    // edge_index[1]
  float* out = (float*)d_out; // [N, 64]

  // workspace layout
  const int Npad = (N + 256) & ~255;
  int*            cnt     = (int*)d_ws;                   // N counters (+ovf_cnt at cnt[N])
  int*            ovf_cnt = cnt + N;                      // 1
  int2*           ovf     = (int2*)(cnt + Npad);          // OVCAP pairs
  unsigned short* slots   = (unsigned short*)(ovf + OVCAP); // N*SLOT u16 (2.56MB)
  float*          hs1     = (float*)(slots + (size_t)N * SLOT); // N*128 f32
  float*          agg1    = hs1 + (size_t)N * HID_F;      // N*128 f32
  float*          hs2     = hs1;                          // reuse: dead after gather-1

  const int B = 256;
  constexpr int NB = 8;

  // ---- binning (shared by both layers) ----
  hipMemsetAsync(cnt, 0, (size_t)(N + 1) * sizeof(int), stream);  // cnt + ovf_cnt
  fill_slot_k<<<((E + 3) / 4 + B - 1) / B, B, 0, stream>>>(src, dst, cnt, slots,
                                                           ovf_cnt, ovf, E);

  // ---- layer 1 ----
  gemm_scale_k<IN_F, HID_F, NB, false>
      <<<(N + NB - 1) / NB, HID_F, 0, stream>>>(x, W1, nullptr, cnt, hs1, N);
  gather_slot_k<HID_F, false>
      <<<((size_t)N * 64 + B - 1) / B, B, 0, stream>>>(cnt, slots, ovf_cnt, ovf,
                                                       hs1, nullptr, agg1, N);

  // ---- layer 2 (b1+relu folded into GEMM load; b2 folded into gather store) ----
  gemm_scale_k<HID_F, OUT_F, NB, true>
      <<<(N + NB - 1) / NB, OUT_F, 0, stream>>>(agg1, W2, b1, cnt, hs2, N);
  gather_slot_k<OUT_F, true>
      <<<((size_t)N * 64 + B - 1) / B, B, 0, stream>>>(cnt, slots, ovf_cnt, ovf,
                                                       hs2, b2, out, N);
}